// Round 4
// baseline (587.680 us; speedup 1.0000x reference)
//
#include <hip/hip_runtime.h>
#include <math.h>

// alpha-entmax via bisection (ref: entmax.EntmaxBisect, 50 iters).
// R8: depth-2 ROW pipeline with drain-at-consumption.
//   step r: s_waitcnt vmcnt(0)        (row r's loads ready; also drains
//           prev stores/spills/alpha -- ALWAYS correct, no counting)
//           -> issue asm loads(row r+1)   (fly across all of row r's work)
//           -> max/append -> raw-barrier -> wave0 reg-Newton -> raw-barrier
//           -> coalesced float4 stores from registers.
// R7 post-mortem: counted vmcnt(8/16) immediates were broken by compiler-
// inserted VMEM (BLOCK=1024 forces <=128 VGPR -> spills; scratch ops count
// toward vmcnt) -> garbage reads -> NaN. Fix: vmcnt(0) at consumption
// (robust to ANY extra VMEM), and BLOCK=512 + __launch_bounds__(512,2)
// (VGPR cap 256, live set ~170 -> no spills).
// Raw lgkmcnt-only barriers keep the next row's loads in flight across
// block syncs (__syncthreads would drain vmcnt(0) mid-pipeline).
//
// Facts exploited (unchanged R4-R7):
//  * tau >= gmax-1 always => elements with X <= gmax-1 contribute 0 and
//    output exactly 0 (~98% of row). Any running-max LOWER BOUND works as
//    candidate threshold (extras contribute exactly 0 to solve + output).
//  * alpha=1.5: f(tau)=sum max(X-tau,0)^2-1 convex decreasing; monotone
//    Newton from tau_lo, ~8-12 iters (early exit).

#define D_DIM    32000
#define NV4      8000
#define BLOCK    512
#define NWAVE    8
#define NCHUNK   16                // float4 chunks per thread per row
#define PER_WAVE 1000              // float4 per wave (8*1000 = 8000 exact)
#define RPB      4                 // rows per block
#define CAP      6144
#define NCREG    8                 // fast-path: 8 regs/lane = 512 candidates
#define NEWTON_MAX 30
#define NITER    50

typedef float f32x4 __attribute__((ext_vector_type(4)));

__device__ __forceinline__ float wave_sum(float v) {
#pragma unroll
    for (int off = 32; off > 0; off >>= 1) v += __shfl_xor(v, off, 64);
    return v;
}
__device__ __forceinline__ float wave_max(float v) {
#pragma unroll
    for (int off = 32; off > 0; off >>= 1) v = fmaxf(v, __shfl_xor(v, off, 64));
    return v;
}
__device__ __forceinline__ float pf(float z, bool sq, float expo) {
    z = fmaxf(z, 0.0f);
    return sq ? z * z : powf(z, expo);
}
__device__ __forceinline__ unsigned fflip(float f) {
    unsigned u = __float_as_uint(f);
    return u ^ ((u >> 31) ? 0xFFFFFFFFu : 0x80000000u);
}
__device__ __forceinline__ float funflip(unsigned u) {
    return __uint_as_float(u ^ ((u & 0x80000000u) ? 0x80000000u : 0xFFFFFFFFu));
}

// raw block barrier: orders LDS only, leaves vmcnt (row pipeline) alone.
__device__ __forceinline__ void block_sync_lds() {
    asm volatile("s_waitcnt lgkmcnt(0)" ::: "memory");
    __builtin_amdgcn_s_barrier();
    asm volatile("" ::: "memory");
}
// full drain at point of consumption — always correct.
__device__ __forceinline__ void wait_vm0() {
    asm volatile("s_waitcnt vmcnt(0)" ::: "memory");
    __builtin_amdgcn_sched_barrier(0);   // rule #18: no hoisting past the wait
}

// 16 asm loads, back-to-back; memory clobber pins ordering vs C++ stores.
__device__ __forceinline__ void issue_loads(f32x4 (&dst)[NCHUNK],
                                            const float* __restrict__ rowp,
                                            int lane, int wid) {
#pragma unroll
    for (int k = 0; k < NCHUNK; ++k) {
        const int off = (k << 6) + lane;
        const int i4  = wid * PER_WAVE + ((off < PER_WAVE) ? off : PER_WAVE - 1);
        const unsigned boff = (unsigned)i4 * 16u;
        asm volatile("global_load_dwordx4 %0, %1, %2"
                     : "=v"(dst[k]) : "v"(boff), "s"(rowp) : "memory");
    }
}

struct SMem {
    float    val[CAP];     // 24 KB, X-domain candidates
    float    red[NWAVE];
    float    bc[2];        // tau, S
    int      cnt[2];       // ping-pong by row parity
    unsigned gmax[2];      // ping-pong, fflip(X) domain
};

template<bool ISSUE_NEXT>
__device__ __forceinline__ void row_step(
    const float* __restrict__ x, float* __restrict__ out,
    int row, int next_ldrow, int n_rows, int p,
    f32x4 (&cur)[NCHUNK], f32x4 (&nxt)[NCHUNK],
    int tid, int lane, int wid,
    float am1, float inv_am1, float expo, bool sq, SMem& sm)
{
    // 1) cur data ready (drains loads(cur) + prev stores + anything else)
    wait_vm0();
    // 2) launch next row's flight — overlaps ALL of row r's work below
    if constexpr (ISSUE_NEXT)
        issue_loads(nxt, x + (size_t)next_ldrow * D_DIM, lane, wid);
    if (row >= n_rows) return;           // block-uniform

    // 3) tail mask (only k==15, lanes with off >= 1000)
#pragma unroll
    for (int k = 0; k < NCHUNK; ++k)
        if ((k << 6) + lane >= PER_WAVE)
            cur[k] = (f32x4){-INFINITY, -INFINITY, -INFINITY, -INFINITY};

    // 4) wave max -> LDS running max (one round trip)
    float tm = -INFINITY;
#pragma unroll
    for (int k = 0; k < NCHUNK; ++k)
        tm = fmaxf(tm, fmaxf(fmaxf(cur[k][0], cur[k][1]),
                             fmaxf(cur[k][2], cur[k][3])));
    const float wm  = wave_max(tm);
    const float wmX = wm * am1;
    if (lane == 0) atomicMax(&sm.gmax[p], fflip(wmX));
    const unsigned rr = __hip_atomic_load(&sm.gmax[p], __ATOMIC_RELAXED,
                                          __HIP_MEMORY_SCOPE_WORKGROUP);
    const float run   = fmaxf(funflip(rr), wmX);   // any lower bound valid
    const float thr_x = (run - 1.0f) * inv_am1;    // raw-x domain

    // 5) candidate scan + wave-aggregated append
    int cnt = 0;
#pragma unroll
    for (int k = 0; k < NCHUNK; ++k)
        cnt += (cur[k][0] > thr_x) + (cur[k][1] > thr_x)
             + (cur[k][2] > thr_x) + (cur[k][3] > thr_x);
    int inc = cnt;
#pragma unroll
    for (int off = 1; off < 64; off <<= 1) {
        const int t = __shfl_up(inc, off, 64);
        if (lane >= off) inc += t;
    }
    const int wtotal = __shfl(inc, 63, 64);
    if (wtotal > 0) {
        int base = 0;
        if (lane == 63) base = atomicAdd(&sm.cnt[p], wtotal);
        base = __shfl(base, 63, 64);
        int pos = base + (inc - cnt);
#pragma unroll
        for (int k = 0; k < NCHUNK; ++k)
#pragma unroll
            for (int c = 0; c < 4; ++c) {
                const float val = cur[k][c];
                if (val > thr_x) {
                    if (pos < CAP) sm.val[pos] = val * am1;
                    ++pos;
                }
            }
    }
    block_sync_lds();                                 // barrier-1

    const int   n_act   = sm.cnt[p];
    const float max_val = funflip(sm.gmax[p]);
    if (tid == 0) { sm.cnt[p ^ 1] = 0; sm.gmax[p ^ 1] = 0u; }  // reset OTHER slot
    const float tau_lo0 = max_val - 1.0f;

    if (n_act <= NCREG * 64) {
        // ---- fast path: wave0, candidates in registers, pure-VALU Newton
        if (wid == 0) {
            float c[NCREG];
#pragma unroll
            for (int j = 0; j < NCREG; ++j) {
                const int idx = (j << 6) + lane;
                c[j] = (idx < n_act) ? sm.val[idx] : -INFINITY;  // pads: z=0
            }
            float tau, S;
            if (sq) {
                tau = tau_lo0;
                for (int it = 0; it < NEWTON_MAX; ++it) {
                    float s1 = 0.f, s2 = 0.f;
#pragma unroll
                    for (int j = 0; j < NCREG; ++j) {
                        const float z = fmaxf(c[j] - tau, 0.f);
                        s1 += z; s2 += z * z;
                    }
#pragma unroll
                    for (int off = 32; off > 0; off >>= 1) {
                        s1 += __shfl_xor(s1, off, 64);
                        s2 += __shfl_xor(s2, off, 64);
                    }
                    const float dtau = (s2 - 1.0f) / fmaxf(2.0f * s1, 1e-30f);
                    tau += dtau;
                    if (dtau < 1e-7f * fmaxf(1.0f, fabsf(tau))) break;
                }
                float s2 = 0.f;
#pragma unroll
                for (int j = 0; j < NCREG; ++j) {
                    const float z = fmaxf(c[j] - tau, 0.f);
                    s2 += z * z;
                }
                S = wave_sum(s2);
            } else {
                // generic alpha: 50-step bisection over register candidates
                const float tau_hi = max_val - powf(1.0f / (float)D_DIM, am1);
                float dm = tau_hi - tau_lo0;
                float s = 0.f;
#pragma unroll
                for (int j = 0; j < NCREG; ++j) s += pf(c[j] - tau_lo0, sq, expo);
                s = wave_sum(s);
                const float f_lo = s - 1.0f;
                float tlo = tau_lo0, tau_m = tau_lo0, fsum = s;
                for (int it = 0; it < NITER; ++it) {
                    dm *= 0.5f;
                    tau_m = tlo + dm;
                    float t = 0.f;
#pragma unroll
                    for (int j = 0; j < NCREG; ++j) t += pf(c[j] - tau_m, sq, expo);
                    t = wave_sum(t);
                    fsum = t;
                    if ((t - 1.0f) * f_lo >= 0.0f) tlo = tau_m;
                }
                tau = tau_m; S = fsum;
            }
            if (lane == 0) { sm.bc[0] = tau; sm.bc[1] = S; }
        }
    } else if (n_act <= CAP) {
        // ---- mid path: wave0, strided LDS loops (rare)
        if (wid == 0) {
            float tau, S;
            if (sq) {
                tau = tau_lo0;
                for (int it = 0; it < NEWTON_MAX; ++it) {
                    float s1 = 0.f, s2 = 0.f;
                    for (int i = lane; i < n_act; i += 64) {
                        const float z = fmaxf(sm.val[i] - tau, 0.f);
                        s1 += z; s2 += z * z;
                    }
#pragma unroll
                    for (int off = 32; off > 0; off >>= 1) {
                        s1 += __shfl_xor(s1, off, 64);
                        s2 += __shfl_xor(s2, off, 64);
                    }
                    const float dtau = (s2 - 1.0f) / fmaxf(2.0f * s1, 1e-30f);
                    tau += dtau;
                    if (dtau < 1e-7f * fmaxf(1.0f, fabsf(tau))) break;
                }
                float s2 = 0.f;
                for (int i = lane; i < n_act; i += 64) {
                    const float z = fmaxf(sm.val[i] - tau, 0.f);
                    s2 += z * z;
                }
                S = wave_sum(s2);
            } else {
                const float tau_hi = max_val - powf(1.0f / (float)D_DIM, am1);
                float dm = tau_hi - tau_lo0;
                float s = 0.f;
                for (int i = lane; i < n_act; i += 64)
                    s += pf(sm.val[i] - tau_lo0, sq, expo);
                s = wave_sum(s);
                const float f_lo = s - 1.0f;
                float tlo = tau_lo0, tau_m = tau_lo0, fsum = s;
                for (int it = 0; it < NITER; ++it) {
                    dm *= 0.5f;
                    tau_m = tlo + dm;
                    float t = 0.f;
                    for (int i = lane; i < n_act; i += 64)
                        t += pf(sm.val[i] - tau_m, sq, expo);
                    t = wave_sum(t);
                    fsum = t;
                    if ((t - 1.0f) * f_lo >= 0.0f) tlo = tau_m;
                }
                tau = tau_m; S = fsum;
            }
            if (lane == 0) { sm.bc[0] = tau; sm.bc[1] = S; }
        }
    } else {
        // ---- overflow fallback (pathological): block-wide 50-step bisection
        //      over REGISTER data (no global re-read)
        const float tau_hi = max_val - powf(1.0f / (float)D_DIM, am1);
        float dm = tau_hi - tau_lo0;
        float sacc = 0.f;
#pragma unroll
        for (int k = 0; k < NCHUNK; ++k)
#pragma unroll
            for (int c = 0; c < 4; ++c)
                sacc += pf(cur[k][c] * am1 - tau_lo0, sq, expo);
        sacc = wave_sum(sacc);
        if (lane == 0) sm.red[wid] = sacc;
        block_sync_lds();
        float tot = 0.f;
#pragma unroll
        for (int w = 0; w < NWAVE; ++w) tot += sm.red[w];
        const float f_lo = tot - 1.0f;
        float tlo = tau_lo0, tau_m = tau_lo0, fsum = tot;
        for (int it = 0; it < NITER; ++it) {
            block_sync_lds();          // protect red reads from next write
            dm *= 0.5f;
            tau_m = tlo + dm;
            float t = 0.f;
#pragma unroll
            for (int k = 0; k < NCHUNK; ++k)
#pragma unroll
                for (int c = 0; c < 4; ++c)
                    t += pf(cur[k][c] * am1 - tau_m, sq, expo);
            t = wave_sum(t);
            if (lane == 0) sm.red[wid] = t;
            block_sync_lds();
            float tt = 0.f;
#pragma unroll
            for (int w = 0; w < NWAVE; ++w) tt += sm.red[w];
            fsum = tt;
            if ((tt - 1.0f) * f_lo >= 0.0f) tlo = tau_m;
        }
        if (tid == 0) { sm.bc[0] = tau_m; sm.bc[1] = fsum; }
    }
    block_sync_lds();                                 // barrier-2 (tau ready)

    // 6) single coalesced write pass from registers (16 stores/wave)
    const float tau_f = sm.bc[0];
    const float invS  = 1.0f / sm.bc[1];
    float4* __restrict__ o4 = (float4*)(out + (size_t)row * D_DIM);
#pragma unroll
    for (int k = 0; k < NCHUNK; ++k) {
        const int off = (k << 6) + lane;
        if (off < PER_WAVE) {          // k<15 always true; k==15 part-masked
            const int i4 = wid * PER_WAVE + off;
            float4 o;
            { const float z = fmaxf(cur[k][0] * am1 - tau_f, 0.f);
              o.x = (sq ? z * z : powf(z, expo)) * invS; }
            { const float z = fmaxf(cur[k][1] * am1 - tau_f, 0.f);
              o.y = (sq ? z * z : powf(z, expo)) * invS; }
            { const float z = fmaxf(cur[k][2] * am1 - tau_f, 0.f);
              o.z = (sq ? z * z : powf(z, expo)) * invS; }
            { const float z = fmaxf(cur[k][3] * am1 - tau_f, 0.f);
              o.w = (sq ? z * z : powf(z, expo)) * invS; }
            o4[i4] = o;
        }
    }
}

__global__ __launch_bounds__(BLOCK, 2)   // VGPR cap 256: no spills (~170 live)
void entmax_bisect_kernel(const float* __restrict__ x,
                          const float* __restrict__ alpha_p,
                          float* __restrict__ out, int n_rows) {
    __shared__ SMem sm;
    const int tid  = threadIdx.x;
    const int lane = tid & 63;
    const int wid  = tid >> 6;
    const int row0 = blockIdx.x * RPB;

    f32x4 vA[NCHUNK], vB[NCHUNK];

    // prologue: kick off row0 loads before anything else
    const int ld0 = (row0 < n_rows) ? row0 : (n_rows - 1);
    issue_loads(vA, x + (size_t)ld0 * D_DIM, lane, wid);

    const float alpha   = alpha_p[0];
    const float am1     = alpha - 1.0f;
    const float inv_am1 = 1.0f / am1;
    const float expo    = inv_am1;
    const bool  sq      = (expo == 2.0f);   // alpha == 1.5 exact fast path

    if (tid == 0) { sm.cnt[0] = 0; sm.cnt[1] = 0; sm.gmax[0] = 0u; sm.gmax[1] = 0u; }
    block_sync_lds();

    // clamped next-row indices (addresses must stay in-bounds)
    const int r1 = (row0 + 1 < n_rows) ? row0 + 1 : n_rows - 1;
    const int r2 = (row0 + 2 < n_rows) ? row0 + 2 : n_rows - 1;
    const int r3 = (row0 + 3 < n_rows) ? row0 + 3 : n_rows - 1;

    row_step<true >(x, out, row0,     r1, n_rows, 0, vA, vB, tid, lane, wid, am1, inv_am1, expo, sq, sm);
    row_step<true >(x, out, row0 + 1, r2, n_rows, 1, vB, vA, tid, lane, wid, am1, inv_am1, expo, sq, sm);
    row_step<true >(x, out, row0 + 2, r3, n_rows, 0, vA, vB, tid, lane, wid, am1, inv_am1, expo, sq, sm);
    row_step<false>(x, out, row0 + 3, r3, n_rows, 1, vB, vA, tid, lane, wid, am1, inv_am1, expo, sq, sm);
    // final stores drain at end-of-kernel implicit waitcnt
}

extern "C" void kernel_launch(void* const* d_in, const int* in_sizes, int n_in,
                              void* d_out, int out_size, void* d_ws, size_t ws_size,
                              hipStream_t stream) {
    const float* x       = (const float*)d_in[0];
    const float* alpha_p = (const float*)d_in[1];
    float* out           = (float*)d_out;
    const int rows       = in_sizes[0] / D_DIM;          // 2048
    const int nblocks    = (rows + RPB - 1) / RPB;       // 512
    entmax_bisect_kernel<<<nblocks, BLOCK, 0, stream>>>(x, alpha_p, out, rows);
}

// Round 5
// 506.847 us; speedup vs baseline: 1.1595x; 1.1595x over previous
//
#include <hip/hip_runtime.h>
#include <math.h>

// alpha-entmax via bisection (ref: entmax.EntmaxBisect, 50 iters).
// R9: persistent blocks + LDS-staged row pipeline via global_load_lds DMA.
//
// R5/R6/R8 lesson: a full row (64 VGPR/thread) + a prefetch row cannot
// coexist in the register file -- RA remats (R5), squeezes (R6), or
// spills (R8, 295us). So the prefetch buffer lives in LDS: the DMA
// engine (global_load_lds, width 16) streams the NEXT row into a 128KB
// LDS buffer with zero register cost while the CURRENT row (in regs,
// loaded from LDS in ~0.2us) is computed/solved/stored.
//
// Structure (grid 256 = 1 block/CU, RPB=8 rows, pipeline never cold
// after the prologue):
//   loop: vmcnt(0)+barrier (buf=row r ready; R7 lesson: never counted)
//         ds_read row -> regs; barrier (buf free)
//         issue DMA(row r+1)            <- 128KB in flight across below
//         exact row max (s_red, no atomics)
//         exact-threshold gather (~700 cands) -> LDS
//         redundant solve on ALL 8 waves (identical data -> identical tau;
//         no broadcast barrier, no idle waves)
//         coalesced float4 stores from regs
// Per-row floor: 256KB of HBM share @24.6GB/s/CU = 10.4us >> ~2us VALU.
//
// Facts exploited (unchanged): tau >= gmax-1 => elements with
// X <= gmax-1 contribute 0 and output exactly 0 (~98% of row);
// alpha=1.5 => f(tau) convex decreasing, monotone Newton ~8-12 iters.

#define D_DIM    32000
#define NV4      8000
#define BLOCK    512
#define NWAVE    8
#define NCHUNK   16               // float4 per thread (tid + k*512)
#define NDMA     125              // 64-float4 DMA chunks per row
#define RPB      8                // rows per block (grid 256, 2048 exact)
#define CAP      6144
#define NCREG    16               // fast path: 1024 reg candidates
#define NEWTON_MAX 30
#define NITER    50

typedef float f32x4 __attribute__((ext_vector_type(4)));
typedef __attribute__((address_space(1))) const void* as1_cvp;
typedef __attribute__((address_space(3))) void*       as3_vp;

__device__ __forceinline__ float wave_sum(float v) {
#pragma unroll
    for (int off = 32; off > 0; off >>= 1) v += __shfl_xor(v, off, 64);
    return v;
}
__device__ __forceinline__ float wave_max(float v) {
#pragma unroll
    for (int off = 32; off > 0; off >>= 1) v = fmaxf(v, __shfl_xor(v, off, 64));
    return v;
}
__device__ __forceinline__ float pf(float z, bool sq, float expo) {
    z = fmaxf(z, 0.0f);
    return sq ? z * z : powf(z, expo);
}

// raw block barrier: orders LDS only, leaves vmcnt (DMA pipeline) alone.
__device__ __forceinline__ void block_sync_lds() {
    asm volatile("s_waitcnt lgkmcnt(0)" ::: "memory");
    __builtin_amdgcn_s_barrier();
    asm volatile("" ::: "memory");
}
// full drain at point of consumption — always correct (R7 lesson).
__device__ __forceinline__ void wait_vm0() {
    asm volatile("s_waitcnt vmcnt(0)" ::: "memory");
    __builtin_amdgcn_sched_barrier(0);
}

// DMA one row (128 KB) into the LDS buffer. Chunk c covers float4
// [c*64, c*64+64); LDS dest is wave-uniform base + lane*16 (HW rule) ->
// linear layout, chunks disjoint, no cross-wave overlap. Wave w issues
// chunks c = k*8+w (waves 0-4: 16 chunks, 5-7: 15; uniform branches).
__device__ __forceinline__ void dma_row(const float* __restrict__ rowp,
                                        float4* buf, int lane, int wid) {
#pragma unroll
    for (int k = 0; k < 16; ++k) {
        const int c = (k << 3) + wid;
        if (c < NDMA) {
            const float4* gsrc = (const float4*)rowp + (c << 6) + lane;
            float4*       ldst = buf + (c << 6);
            __builtin_amdgcn_global_load_lds(
                (as1_cvp)(const void*)gsrc, (as3_vp)(void*)ldst, 16, 0, 0);
        }
    }
}

struct SMem {
    float4 buf[NV4];      // 128 KB row staging (DMA target)
    float  val[CAP];      // 24 KB candidates (X domain)
    float  red[NWAVE];
    int    cnt[2];        // ping-pong by row parity
};                        // 152,624 B <= 160 KiB

__global__ __launch_bounds__(BLOCK, 1)
void entmax_bisect_kernel(const float* __restrict__ x,
                          const float* __restrict__ alpha_p,
                          float* __restrict__ out, int n_rows) {
    __shared__ SMem sm;
    const int tid  = threadIdx.x;
    const int lane = tid & 63;
    const int wid  = tid >> 6;

    const float alpha   = alpha_p[0];
    const float am1     = alpha - 1.0f;
    const float inv_am1 = 1.0f / am1;
    const float expo    = inv_am1;
    const bool  sq      = (expo == 2.0f);    // alpha == 1.5 exact fast path

    if (tid == 0) { sm.cnt[0] = 0; sm.cnt[1] = 0; }

    const int row0 = blockIdx.x * RPB;
    {   // prologue: start row0's DMA immediately
        const int r = (row0 < n_rows) ? row0 : (n_rows - 1);
        dma_row(x + (size_t)r * D_DIM, sm.buf, lane, wid);
    }

    for (int i = 0; i < RPB; ++i) {
        const int rowi = row0 + i;
        const int row  = (rowi < n_rows) ? rowi : (n_rows - 1);
        const int p    = i & 1;

        // ---- B0: buffer holds row r, everywhere ----
        wait_vm0();              // own DMA chunks + prev-row stores done
        block_sync_lds();        // all waves drained -> whole buf valid

        // ---- LDS -> regs (~128KB at LDS BW, ~0.2us) ----
        f32x4 v[NCHUNK];
#pragma unroll
        for (int k = 0; k < NCHUNK; ++k) {
            const int i4 = tid + (k << 9);
            if (i4 < NV4) {
                const float4 t = sm.buf[i4];
                v[k] = (f32x4){t.x, t.y, t.z, t.w};
            } else {
                v[k] = (f32x4){-INFINITY, -INFINITY, -INFINITY, -INFINITY};
            }
        }
        block_sync_lds();        // B0b: all reads retired -> buf free

        // ---- launch next row's DMA; flies across everything below ----
        if (i + 1 < RPB) {
            const int rn = (rowi + 1 < n_rows) ? rowi + 1 : (n_rows - 1);
            dma_row(x + (size_t)rn * D_DIM, sm.buf, lane, wid);
        }

        // ---- exact row max (no atomics) ----
        float tm = -INFINITY;
#pragma unroll
        for (int k = 0; k < NCHUNK; ++k)
            tm = fmaxf(tm, fmaxf(fmaxf(v[k][0], v[k][1]),
                                 fmaxf(v[k][2], v[k][3])));
        const float wm = wave_max(tm);
        if (lane == 0) sm.red[wid] = wm;
        block_sync_lds();        // B1
        float gx = sm.red[0];
#pragma unroll
        for (int w = 1; w < NWAVE; ++w) gx = fmaxf(gx, sm.red[w]);
        const float maxX    = gx * am1;              // exact global max, X dom
        const float tau_lo0 = maxX - 1.0f;
        const float thr_x   = tau_lo0 * inv_am1;     // exact thr, raw-x domain

        // ---- candidate gather (exact threshold), wave-aggregated ----
        int cnt = 0;
#pragma unroll
        for (int k = 0; k < NCHUNK; ++k)
            cnt += (v[k][0] > thr_x) + (v[k][1] > thr_x)
                 + (v[k][2] > thr_x) + (v[k][3] > thr_x);
        int inc = cnt;
#pragma unroll
        for (int off = 1; off < 64; off <<= 1) {
            const int t = __shfl_up(inc, off, 64);
            if (lane >= off) inc += t;
        }
        const int wtotal = __shfl(inc, 63, 64);
        if (wtotal > 0) {
            int base = 0;
            if (lane == 63) base = atomicAdd(&sm.cnt[p], wtotal);
            base = __shfl(base, 63, 64);
            int pos = base + (inc - cnt);
#pragma unroll
            for (int k = 0; k < NCHUNK; ++k)
#pragma unroll
                for (int c2 = 0; c2 < 4; ++c2) {
                    const float val = v[k][c2];
                    if (val > thr_x) {
                        if (pos < CAP) sm.val[pos] = val * am1;
                        ++pos;
                    }
                }
        }
        block_sync_lds();        // B2
        const int n_act = sm.cnt[p];
        if (tid == 0) sm.cnt[p ^ 1] = 0;   // reset other slot (>=2 barriers
                                           // before its next use)
        float tau, S;
        if (n_act <= NCREG * 64) {
            // ---- fast path: ALL waves solve redundantly from registers
            //      (identical data -> bitwise-identical tau; no broadcast)
            float c[NCREG];
#pragma unroll
            for (int j = 0; j < NCREG; ++j) {
                const int idx = (j << 6) + lane;
                c[j] = (idx < n_act) ? sm.val[idx] : -INFINITY;  // pads: z=0
            }
            if (sq) {
                tau = tau_lo0;                   // monotone Newton
                for (int it = 0; it < NEWTON_MAX; ++it) {
                    float s1 = 0.f, s2 = 0.f;
#pragma unroll
                    for (int j = 0; j < NCREG; ++j) {
                        const float z = fmaxf(c[j] - tau, 0.f);
                        s1 += z; s2 += z * z;
                    }
#pragma unroll
                    for (int off = 32; off > 0; off >>= 1) {
                        s1 += __shfl_xor(s1, off, 64);
                        s2 += __shfl_xor(s2, off, 64);
                    }
                    const float dtau = (s2 - 1.0f) / fmaxf(2.0f * s1, 1e-30f);
                    tau += dtau;
                    if (dtau < 1e-7f * fmaxf(1.0f, fabsf(tau))) break;
                }
                float s2 = 0.f;
#pragma unroll
                for (int j = 0; j < NCREG; ++j) {
                    const float z = fmaxf(c[j] - tau, 0.f);
                    s2 += z * z;
                }
                S = wave_sum(s2);
            } else {
                // generic alpha: faithful 50-step bisection over candidates
                const float tau_hi = maxX - powf(1.0f / (float)D_DIM, am1);
                float dm = tau_hi - tau_lo0;
                float s = 0.f;
#pragma unroll
                for (int j = 0; j < NCREG; ++j) s += pf(c[j] - tau_lo0, sq, expo);
                s = wave_sum(s);
                const float f_lo = s - 1.0f;
                float tlo = tau_lo0, tau_m = tau_lo0, fsum = s;
                for (int it = 0; it < NITER; ++it) {
                    dm *= 0.5f;
                    tau_m = tlo + dm;
                    float t = 0.f;
#pragma unroll
                    for (int j = 0; j < NCREG; ++j) t += pf(c[j] - tau_m, sq, expo);
                    t = wave_sum(t);
                    fsum = t;
                    if ((t - 1.0f) * f_lo >= 0.0f) tlo = tau_m;
                }
                tau = tau_m; S = fsum;
            }
        } else if (n_act <= CAP) {
            // ---- mid path: redundant per-wave strided LDS Newton (rare)
            if (sq) {
                tau = tau_lo0;
                for (int it = 0; it < NEWTON_MAX; ++it) {
                    float s1 = 0.f, s2 = 0.f;
                    for (int idx = lane; idx < n_act; idx += 64) {
                        const float z = fmaxf(sm.val[idx] - tau, 0.f);
                        s1 += z; s2 += z * z;
                    }
#pragma unroll
                    for (int off = 32; off > 0; off >>= 1) {
                        s1 += __shfl_xor(s1, off, 64);
                        s2 += __shfl_xor(s2, off, 64);
                    }
                    const float dtau = (s2 - 1.0f) / fmaxf(2.0f * s1, 1e-30f);
                    tau += dtau;
                    if (dtau < 1e-7f * fmaxf(1.0f, fabsf(tau))) break;
                }
                float s2 = 0.f;
                for (int idx = lane; idx < n_act; idx += 64) {
                    const float z = fmaxf(sm.val[idx] - tau, 0.f);
                    s2 += z * z;
                }
                S = wave_sum(s2);
            } else {
                const float tau_hi = maxX - powf(1.0f / (float)D_DIM, am1);
                float dm = tau_hi - tau_lo0;
                float s = 0.f;
                for (int idx = lane; idx < n_act; idx += 64)
                    s += pf(sm.val[idx] - tau_lo0, sq, expo);
                s = wave_sum(s);
                const float f_lo = s - 1.0f;
                float tlo = tau_lo0, tau_m = tau_lo0, fsum = s;
                for (int it = 0; it < NITER; ++it) {
                    dm *= 0.5f;
                    tau_m = tlo + dm;
                    float t = 0.f;
                    for (int idx = lane; idx < n_act; idx += 64)
                        t += pf(sm.val[idx] - tau_m, sq, expo);
                    t = wave_sum(t);
                    fsum = t;
                    if ((t - 1.0f) * f_lo >= 0.0f) tlo = tau_m;
                }
                tau = tau_m; S = fsum;
            }
        } else {
            // ---- overflow fallback (pathological): block-wide bisection over
            //      register data; every thread derives identical tau/S.
            const float tau_hi = maxX - powf(1.0f / (float)D_DIM, am1);
            float dm = tau_hi - tau_lo0;
            float sacc = 0.f;
#pragma unroll
            for (int k = 0; k < NCHUNK; ++k)
#pragma unroll
                for (int c2 = 0; c2 < 4; ++c2)
                    sacc += pf(v[k][c2] * am1 - tau_lo0, sq, expo);
            sacc = wave_sum(sacc);
            if (lane == 0) sm.red[wid] = sacc;
            block_sync_lds();
            float tot = 0.f;
#pragma unroll
            for (int w = 0; w < NWAVE; ++w) tot += sm.red[w];
            const float f_lo = tot - 1.0f;
            float tlo = tau_lo0, tau_m = tau_lo0, fsum = tot;
            for (int it = 0; it < NITER; ++it) {
                block_sync_lds();          // protect red reads vs next write
                dm *= 0.5f;
                tau_m = tlo + dm;
                float t = 0.f;
#pragma unroll
                for (int k = 0; k < NCHUNK; ++k)
#pragma unroll
                    for (int c2 = 0; c2 < 4; ++c2)
                        t += pf(v[k][c2] * am1 - tau_m, sq, expo);
                t = wave_sum(t);
                if (lane == 0) sm.red[wid] = t;
                block_sync_lds();
                float tt = 0.f;
#pragma unroll
                for (int w = 0; w < NWAVE; ++w) tt += sm.red[w];
                fsum = tt;
                if ((tt - 1.0f) * f_lo >= 0.0f) tlo = tau_m;
            }
            tau = tau_m; S = fsum;
        }

        // ---- coalesced write pass from registers ----
        const float invS = 1.0f / S;
        float4* __restrict__ o4 = (float4*)(out + (size_t)row * D_DIM);
#pragma unroll
        for (int k = 0; k < NCHUNK; ++k) {
            const int i4 = tid + (k << 9);
            if (i4 < NV4) {
                float4 o;
                { const float z = fmaxf(v[k][0] * am1 - tau, 0.f);
                  o.x = (sq ? z * z : powf(z, expo)) * invS; }
                { const float z = fmaxf(v[k][1] * am1 - tau, 0.f);
                  o.y = (sq ? z * z : powf(z, expo)) * invS; }
                { const float z = fmaxf(v[k][2] * am1 - tau, 0.f);
                  o.z = (sq ? z * z : powf(z, expo)) * invS; }
                { const float z = fmaxf(v[k][3] * am1 - tau, 0.f);
                  o.w = (sq ? z * z : powf(z, expo)) * invS; }
                o4[i4] = o;
            }
        }
        // stores drain at next iteration's wait_vm0 (or end-of-kernel)
    }
}

extern "C" void kernel_launch(void* const* d_in, const int* in_sizes, int n_in,
                              void* d_out, int out_size, void* d_ws, size_t ws_size,
                              hipStream_t stream) {
    const float* x       = (const float*)d_in[0];
    const float* alpha_p = (const float*)d_in[1];
    float* out           = (float*)d_out;
    const int rows       = in_sizes[0] / D_DIM;          // 2048
    const int nblocks    = (rows + RPB - 1) / RPB;       // 256
    entmax_bisect_kernel<<<nblocks, BLOCK, 0, stream>>>(x, alpha_p, out, rows);
}